// Round 18
// baseline (245.549 us; speedup 1.0000x reference)
//
#include <hip/hip_runtime.h>
#include <stdint.h>

#define NP 1024
#define NV 49408
#define ND 512
// BOTH operands packed FRAGMENT-ORDERED (1 KB contiguous per wave-fragment):
//   A: chunk(t, mb, lane) at byte ((t*64 + mb)*64 + lane)*16, t in 0..31
//      (phys 32-k tile: 0-15 hi, 16-31 lo), mb = row>>4, lane = g*16 + r
//      holds A[mb*16+r][t*32 + g*8 .. +7].
//   B: chunk(t, nb, lane) at byte ((t*3088 + nb)*64 + lane)*16, nb = row>>4,
//      same per-lane mapping (r = row&15, g = k-group).
// Logical K=1536, 3-term split, 32-k steps -> 48 logical tiles:
//   A phys tile = t & 31                      (ah x16, al x16, ah x16)
//   B phys tile = (t & 15) + (t>=32 ? 16 : 0) (bh, bh, bl)
#define NTILE 48
#define BSTRIDE 3162112   // 3088 * 1024 bytes per B phys tile

typedef __attribute__((ext_vector_type(8))) __bf16 bf16x8;
typedef __attribute__((ext_vector_type(4))) float f32x4;

__device__ inline unsigned long long pack_sv(float s, unsigned v) {
  unsigned u = __float_as_uint(s);
  u = (u & 0x80000000u) ? ~u : (u | 0x80000000u);  // orderable map
  return ((unsigned long long)u << 32) | (unsigned long long)v;
}

// A-pack: bf16 hi/lo split, fragment-ordered.
__global__ __launch_bounds__(256) void pack_a_k(const float* __restrict__ src,
                                                __bf16* __restrict__ dst) {
  int lane = threadIdx.x & 63;
  int row = blockIdx.x * 4 + (threadIdx.x >> 6);
  const float* r = src + (size_t)row * ND + lane * 8;
  float4 x0 = *(const float4*)r;
  float4 x1 = *(const float4*)(r + 4);
  float xs[8] = {x0.x, x0.y, x0.z, x0.w, x1.x, x1.y, x1.z, x1.w};
  bf16x8 hi, lo;
#pragma unroll
  for (int j = 0; j < 8; ++j) {
    float x = xs[j];
    __bf16 h = (__bf16)x;
    hi[j] = h;
    lo[j] = (__bf16)(x - (float)h);   // exact residual, then RTNE to bf16
  }
  const int mb = row >> 4, rr = row & 15;
  const int tHi = lane >> 2, g = lane & 3;
  size_t cHi = (((size_t)tHi * 64) + mb) * 64 + g * 16 + rr;
  size_t cLo = (((size_t)(tHi + 16) * 64) + mb) * 64 + g * 16 + rr;
  *(bf16x8*)(dst + cHi * 8) = hi;
  *(bf16x8*)(dst + cLo * 8) = lo;
}

// B-pack: bf16 hi/lo split, fragment-ordered + exact f32 sum of squares.
__global__ __launch_bounds__(256) void pack_b_k(const float* __restrict__ src,
                                                __bf16* __restrict__ dst,
                                                float* __restrict__ sumsq) {
  int lane = threadIdx.x & 63;
  int row = blockIdx.x * 4 + (threadIdx.x >> 6);
  const float* r = src + (size_t)row * ND + lane * 8;
  float4 x0 = *(const float4*)r;
  float4 x1 = *(const float4*)(r + 4);
  float xs[8] = {x0.x, x0.y, x0.z, x0.w, x1.x, x1.y, x1.z, x1.w};
  bf16x8 hi, lo;
  float ss = 0.f;
#pragma unroll
  for (int j = 0; j < 8; ++j) {
    float x = xs[j];
    ss += x * x;
    __bf16 h = (__bf16)x;
    hi[j] = h;
    lo[j] = (__bf16)(x - (float)h);
  }
  const int nb = row >> 4, rr = row & 15;
  const int tHi = lane >> 2, g = lane & 3;
  size_t cHi = (((size_t)tHi * 3088) + nb) * 64 + g * 16 + rr;
  size_t cLo = (((size_t)(tHi + 16) * 3088) + nb) * 64 + g * 16 + rr;
  *(bf16x8*)(dst + cHi * 8) = hi;
  *(bf16x8*)(dst + cLo * 8) = lo;
#pragma unroll
  for (int m = 1; m < 64; m <<= 1) ss += __shfl_xor(ss, m);
  if (lane == 0) sumsq[row] = ss;
}

// ---- 128x128 tile, 4 waves, 3 blocks/CU, ZERO-LDS register-dbuf GEMM -------
// Both operands direct global->register from fragment-ordered layouts
// (1 KB contiguous per fragment load, L1/L2-served). Double-buffered one
// K-tile ahead; NO LDS, NO barriers, NO hand waitcnts - pure data flow, so
// the compiler's waitcnt pass tracks every load precisely and waves
// free-run (m114 overlap regime). Reuse comes from L1/L2: wn-pair waves
// share A lines; the 3 co-resident blocks share the same B panel chunk
// (XCD swizzle makes consecutive blocks = same bn).
// REGISTER BUDGET: acc(64 AGPR) + 16 frags(64 VGPR) + addr ~145 <= 170
// from (256,3). Watch WRITE_SIZE for spill (R9/R16 lesson).

#define FENCE asm volatile("" ::: "memory")

__device__ __attribute__((always_inline)) static inline
int bTileByte(int t) {               // B phys byte offset for logical tile t
  int tt = (t < NTILE) ? t : t - NTILE;      // wrap: dead prefetch, in-bounds
  return ((tt & 15) + (tt >= 32 ? 16 : 0)) * BSTRIDE;
}

template <int J>
__device__ __attribute__((always_inline)) static inline
void phase_op(f32x4 (&acc)[4][4], bf16x8 (&aE)[4], bf16x8 (&aO)[4],
              bf16x8 (&bE)[4], bf16x8 (&bO)[4],
              const char* Ab, const int (&voffA)[4],
              const char* Bb, const int (&voffB)[4], int t) {
  const int kA = ((t + 1) & 31) * 65536;     // A tile t+1 (wrap: dead)
  const int kB = bTileByte(t + 1);           // B tile t+1
  bf16x8 (&aN)[4] = (J == 0) ? aO : aE;      // prefetch target
  bf16x8 (&aC)[4] = (J == 0) ? aE : aO;      // compute source
  bf16x8 (&bN)[4] = (J == 0) ? bO : bE;
  bf16x8 (&bC)[4] = (J == 0) ? bE : bO;
  // prefetch next K-tile's fragments (plain loads; compiler tracks deps)
#pragma unroll
  for (int m = 0; m < 4; ++m)
    aN[m] = *(const bf16x8*)(Ab + voffA[m] + kA);
#pragma unroll
  for (int n = 0; n < 4; ++n)
    bN[n] = *(const bf16x8*)(Bb + voffB[n] + kB);
  __builtin_amdgcn_s_setprio(1);
#pragma unroll
  for (int m = 0; m < 4; ++m)
#pragma unroll
    for (int n = 0; n < 4; ++n)
      acc[m][n] = __builtin_amdgcn_mfma_f32_16x16x32_bf16(aC[m], bC[n], acc[m][n], 0, 0, 0);
  __builtin_amdgcn_s_setprio(0);
}

__global__ __launch_bounds__(256, 3) void gemm_argmin_k(const __bf16* __restrict__ A,
                                                        const __bf16* __restrict__ B,
                                                        const float* __restrict__ b2,
                                                        unsigned long long* __restrict__ best) {
  const int tid = threadIdx.x;
  const int lane = tid & 63;
  const int wid = tid >> 6;   // 0..3
  const int wm = wid >> 1;    // 2 wave-rows (64 rows each)
  const int wn = wid & 1;     // 2 wave-cols (64 cols each)

  // XCD-chunk swizzle (3088 % 8 == 0 -> bijective): 8 M-blocks of a B-panel
  // land on one XCD -> panel L2-resident; co-resident blocks share B lines.
  const int d = blockIdx.x;
  const int o = (d & 7) * 386 + (d >> 3);
  const int bm = (o & 7) * 128;
  const int bn = (o >> 3) * 128;

  const int r = lane & 15, g = lane >> 4;
  (void)g;

  // fragment-ordered per-lane byte offsets
  const char* Ab = (const char*)A;
  const char* Bb = (const char*)B;
  int voffA[4], voffB[4];
#pragma unroll
  for (int m = 0; m < 4; ++m)
    voffA[m] = ((bm >> 4) + wm * 4 + m) * 1024 + lane * 16;
#pragma unroll
  for (int n = 0; n < 4; ++n)
    voffB[n] = ((bn >> 4) + wn * 4 + n) * 1024 + lane * 16;

  f32x4 acc[4][4] = {};
  bf16x8 aE[4], aO[4], bE[4], bO[4];

  // prologue: tile 0 -> E buffers
#pragma unroll
  for (int m = 0; m < 4; ++m)
    aE[m] = *(const bf16x8*)(Ab + voffA[m]);
#pragma unroll
  for (int n = 0; n < 4; ++n)
    bE[n] = *(const bf16x8*)(Bb + voffB[n]);

#pragma unroll 1
  for (int it = 0; it < NTILE / 2; ++it) {
    phase_op<0>(acc, aE, aO, bE, bO, Ab, voffA, Bb, voffB, 2 * it);
    phase_op<1>(acc, aE, aO, bE, bO, Ab, voffA, Bb, voffB, 2 * it + 1);
  }

  // epilogue: fused argmin. C/D map: col = lane&15, row = (lane>>4)*4 + reg.
  const int gg = lane >> 4;
  float bb[4];
#pragma unroll
  for (int n = 0; n < 4; ++n) bb[n] = b2[bn + wn * 64 + n * 16 + r];
#pragma unroll
  for (int m = 0; m < 4; ++m) {
#pragma unroll
    for (int reg = 0; reg < 4; ++reg) {
      unsigned long long pk = ~0ull;
#pragma unroll
      for (int n = 0; n < 4; ++n) {
        float s = bb[n] - 2.0f * acc[m][n][reg];
        unsigned long long cand = pack_sv(s, (unsigned)(bn + wn * 64 + n * 16 + r));
        pk = (cand < pk) ? cand : pk;
      }
#pragma unroll
      for (int msk = 1; msk < 16; msk <<= 1) {
        unsigned long long o2 = __shfl_xor(pk, msk);
        pk = (o2 < pk) ? o2 : pk;
      }
      if (r == 0) atomicMin(&best[bm + wm * 64 + m * 16 + gg * 4 + reg], pk);
    }
  }
}

// Fallback (small ws): exact fp32 squared distance, fused argmin.
__global__ __launch_bounds__(256) void naive_argmin_k(const float* __restrict__ A,
                                                      const float* __restrict__ B,
                                                      unsigned long long* __restrict__ best) {
  __shared__ float arow[ND];
  int p = blockIdx.y;
  unsigned v = blockIdx.x * 256 + threadIdx.x;
  for (int i = threadIdx.x; i < ND; i += 256) arow[i] = A[(size_t)p * ND + i];
  __syncthreads();
  const float4* br = (const float4*)(B + (size_t)v * ND);
  float s = 0.f;
#pragma unroll 4
  for (int i = 0; i < ND / 4; ++i) {
    float4 b = br[i];
    const float4 a = *(const float4*)&arow[i * 4];
    float d0 = a.x - b.x, d1 = a.y - b.y, d2 = a.z - b.z, d3 = a.w - b.w;
    s += d0 * d0 + d1 * d1 + d2 * d2 + d3 * d3;
  }
  unsigned long long pk = pack_sv(s, v);
#pragma unroll
  for (int msk = 1; msk < 64; msk <<= 1) {
    unsigned long long o = __shfl_xor(pk, msk);
    pk = (o < pk) ? o : pk;
  }
  if ((threadIdx.x & 63) == 0) atomicMin(&best[p], pk);
}

// Gather winning rows + ids (ids written as float, d_out is read as flat f32).
__global__ __launch_bounds__(128) void gather_k(const unsigned long long* __restrict__ best,
                                                const float* __restrict__ clip,
                                                float* __restrict__ out) {
  int p = blockIdx.x;
  unsigned long long pk = best[p];
  unsigned v = (unsigned)(pk & 0xffffffffull);
  const float4* src = (const float4*)(clip + (size_t)v * ND);
  float4* dst = (float4*)(out + (size_t)p * ND);
  dst[threadIdx.x] = src[threadIdx.x];
  if (threadIdx.x == 0) out[(size_t)NP * ND + p] = (float)v;
}

extern "C" void kernel_launch(void* const* d_in, const int* in_sizes, int n_in,
                              void* d_out, int out_size, void* d_ws, size_t ws_size,
                              hipStream_t stream) {
  const float* prompt = (const float*)d_in[0];
  const float* clip = (const float*)d_in[1];
  float* out = (float*)d_out;

  // workspace layout
  size_t off = 0;
  unsigned long long* best = (unsigned long long*)d_ws;
  off += (size_t)NP * 8;
  float* b2 = (float*)((char*)d_ws + off);
  off += (size_t)NV * 4;
  off = (off + 255) & ~(size_t)255;
  __bf16* Ap = (__bf16*)((char*)d_ws + off);
  off += (size_t)NP * 1024 * 2;                // 2 MiB  fragment-ordered
  __bf16* Bp = (__bf16*)((char*)d_ws + off);
  off += (size_t)NV * 1024 * 2;                // 96.5 MiB fragment-ordered
  const size_t need = off;

  if (ws_size >= need) {
    hipMemsetAsync(best, 0xFF, (size_t)NP * 8, stream);
    pack_a_k<<<NP / 4, 256, 0, stream>>>(prompt, Ap);
    pack_b_k<<<NV / 4, 256, 0, stream>>>(clip, Bp, b2);
    gemm_argmin_k<<<dim3(8 * 386), 256, 0, stream>>>(Ap, Bp, b2, best);
    gather_k<<<NP, 128, 0, stream>>>(best, clip, out);
  } else {
    // fallback: exact fp32, needs only the 8 KiB `best` array
    hipMemsetAsync(best, 0xFF, (size_t)NP * 8, stream);
    dim3 grid(NV / 256, NP);
    naive_argmin_k<<<grid, 256, 0, stream>>>(prompt, clip, best);
    gather_k<<<NP, 128, 0, stream>>>(best, clip, out);
  }
}

// Round 19
// 219.374 us; speedup vs baseline: 1.1193x; 1.1193x over previous
//
#include <hip/hip_runtime.h>
#include <stdint.h>

#define NP 1024
#define NV 49408
#define ND 512
// B packed: [row][hi(512)|lo(512)] bf16 (2048 B/row). B phys tile p (0..31):
//   byte = (p&15)*64 + (p>=16 ? 1024 : 0)   (p<16: bh ; p>=16: bl)
// A packed FRAGMENT-ORDERED: chunk(t, mb, lane) at byte ((t*64+mb)*64+lane)*16
//   t = phys 32-k tile (0..31: 16 hi, 16 lo), mb = row>>4, lane = g*16 + r.
// Logical K=1536, 3-term split, PAIRED phase order (24 superphases):
//   j=0..15:  logical (j, j+16)       = ah_j*bh_j, al_j*bh_j  -> B SHARED
//   j=16..23: logical (32+2i, 33+2i)  = ah*bl pairs (i=j-16)

typedef __attribute__((ext_vector_type(8))) __bf16 bf16x8;
typedef __attribute__((ext_vector_type(4))) float f32x4;
typedef __attribute__((ext_vector_type(4))) int i32x4;

__device__ inline unsigned long long pack_sv(float s, unsigned v) {
  unsigned u = __float_as_uint(s);
  u = (u & 0x80000000u) ? ~u : (u | 0x80000000u);  // orderable map
  return ((unsigned long long)u << 32) | (unsigned long long)v;
}

// A-pack: bf16 hi/lo split, FRAGMENT-ORDERED layout.
__global__ __launch_bounds__(256) void pack_a_k(const float* __restrict__ src,
                                                __bf16* __restrict__ dst) {
  int lane = threadIdx.x & 63;
  int row = blockIdx.x * 4 + (threadIdx.x >> 6);
  const float* r = src + (size_t)row * ND + lane * 8;
  float4 x0 = *(const float4*)r;
  float4 x1 = *(const float4*)(r + 4);
  float xs[8] = {x0.x, x0.y, x0.z, x0.w, x1.x, x1.y, x1.z, x1.w};
  bf16x8 hi, lo;
#pragma unroll
  for (int j = 0; j < 8; ++j) {
    float x = xs[j];
    __bf16 h = (__bf16)x;
    hi[j] = h;
    lo[j] = (__bf16)(x - (float)h);   // exact residual, then RTNE to bf16
  }
  const int mb = row >> 4, rr = row & 15;
  const int tHi = lane >> 2, g = lane & 3;
  size_t cHi = (((size_t)tHi * 64) + mb) * 64 + g * 16 + rr;
  size_t cLo = (((size_t)(tHi + 16) * 64) + mb) * 64 + g * 16 + rr;
  *(bf16x8*)(dst + cHi * 8) = hi;
  *(bf16x8*)(dst + cLo * 8) = lo;
}

// B-pack: [row][hi|lo] + exact f32 sum of squares per row.
__global__ __launch_bounds__(256) void pack_b_k(const float* __restrict__ src,
                                                __bf16* __restrict__ dst,
                                                float* __restrict__ sumsq) {
  int lane = threadIdx.x & 63;
  int row = blockIdx.x * 4 + (threadIdx.x >> 6);
  const float* r = src + (size_t)row * ND + lane * 8;
  float4 x0 = *(const float4*)r;
  float4 x1 = *(const float4*)(r + 4);
  float xs[8] = {x0.x, x0.y, x0.z, x0.w, x1.x, x1.y, x1.z, x1.w};
  bf16x8 hi, lo;
  float ss = 0.f;
#pragma unroll
  for (int j = 0; j < 8; ++j) {
    float x = xs[j];
    ss += x * x;
    __bf16 h = (__bf16)x;
    hi[j] = h;
    lo[j] = (__bf16)(x - (float)h);
  }
  __bf16* drow = dst + (size_t)row * 1024 + lane * 8;
  *(bf16x8*)drow = hi;
  *(bf16x8*)(drow + 512) = lo;
#pragma unroll
  for (int m = 1; m < 64; m <<= 1) ss += __shfl_xor(ss, m);
  if (lane == 0) sumsq[row] = ss;
}

// ---- 128x128, 4 waves, 3 blocks/CU, PAIRED-B super-phase pipeline ----------
// R17 skeleton (proven absmax=0) + B-tile sharing: phases j<16 compute
// (ah_j*bh_j, al_j*bh_j) with ONE staged B tile (b1==b0 in regs). B-stage
// bytes -50% and LDS reads -33% vs R17 on 2/3 of K.
// Per phase: [D: stage B for phase j+2] [b reads] [W1] [MFMA1(aE,b0)]
//   [PE: A for (j+1).MFMA1] [W2] [MFMA2(aO, TK? b1:b0)] [PO: A for
//   (j+1).MFMA2] [s_barrier].
// Counted waits (derived, heterogeneous): W1=W2=vmcnt(4+#gll16_this) ->
// at W1 retains {D_this, PO_prev}, forcing PE_prev (=MFMA1 operand) and
// D_prev (published by this barrier, read next phase); at W2 retains
// {PE_this, D_this}, forcing PO_prev (=MFMA2 operand). lgkm: W1 = (TK?4:0)
// forces b0; W2 = 0 forces b1. 6-region x 8KB rotation, stage distance 2
// phases; all RAW/WAR edges re-verified incl. j=14..16 transition and the
// dead tail stages (j=22,23 -> regions whose last read was >=3 phases prior).
// REGISTER BUDGET: acc(64 AGPR)+aE/aO(32)+b0/b1(32)+addr ~145 <= 170 (256,3).
// B slot swizzle (R6-verified, 0 conflicts).

__device__ __attribute__((always_inline)) static inline
void gll16(const char* src, char* dst) {
  __builtin_amdgcn_global_load_lds(
      (const __attribute__((address_space(1))) void*)src,
      (__attribute__((address_space(3))) void*)dst, 16, 0, 0);
}

__device__ __attribute__((always_inline)) static inline
bf16x8 lds_read(unsigned addr) {
  i32x4 d;
  asm volatile("ds_read_b128 %0, %1" : "=v"(d) : "v"(addr));
  return __builtin_bit_cast(bf16x8, d);
}

#define FENCE asm volatile("" ::: "memory")

template <int J>
__device__ __attribute__((always_inline)) static inline
void phase_op(f32x4 (&acc)[4][4], bf16x8 (&aE)[4], bf16x8 (&aO)[4],
              const char* Ab, const int (&voffA)[4],
              const char* srcBt, char* stB, unsigned bRead) {
  constexpr bool TK = (J >= 16);
  constexpr int Q = J + 2, QA = J + 1;
  // read regions for THIS phase
  constexpr int RB0 = TK ? (16 + 2 * (J - 16)) % 6 : (J % 6);
  constexpr int RB1 = TK ? (17 + 2 * (J - 16)) % 6 : 0;
  // stage plan for phase Q
  constexpr int DN = (Q <= 15) ? 1 : 2;                    // tiles staged
  constexpr int SP0 = (Q <= 15) ? Q : (Q <= 23 ? 16 + 2 * (Q - 16) : (Q == 24 ? 0 : 2));
  constexpr int SP1 = (Q <= 15) ? 0 : (Q <= 23 ? 17 + 2 * (Q - 16) : (Q == 24 ? 1 : 3));
  constexpr int SR0 = (Q <= 15) ? (Q % 6) : ((16 + 2 * (Q - 16)) % 6);
  constexpr int SR1 = (Q <= 15) ? 0 : ((17 + 2 * (Q - 16)) % 6);
  constexpr int kB0 = (SP0 & 15) * 64 + (SP0 >= 16 ? 1024 : 0);
  constexpr int kB1 = (SP1 & 15) * 64 + (SP1 >= 16 ? 1024 : 0);
  // A prefetch targets (phase QA's operands)
  constexpr int kAE = (QA <= 15 ? QA : (QA <= 23 ? 2 * (QA - 16) : 0)) * 65536;
  constexpr int kAO = (QA <= 15 ? QA + 16 : (QA <= 23 ? 2 * (QA - 16) + 1 : 1)) * 65536;

  // D: stage
  gll16(srcBt + kB0, stB + SR0 * 8192);
  gll16(srcBt + kB0 + 131072, stB + SR0 * 8192 + 4096);
  if constexpr (DN == 2) {
    gll16(srcBt + kB1, stB + SR1 * 8192);
    gll16(srcBt + kB1 + 131072, stB + SR1 * 8192 + 4096);
  }
  // b reads
  bf16x8 b0[4], b1[4];
#pragma unroll
  for (int n = 0; n < 4; ++n) b0[n] = lds_read(bRead + RB0 * 8192 + n * 1024);
  if constexpr (TK) {
#pragma unroll
    for (int n = 0; n < 4; ++n) b1[n] = lds_read(bRead + RB1 * 8192 + n * 1024);
  }
  // W1
  if constexpr (TK) asm volatile("s_waitcnt vmcnt(8) lgkmcnt(4)" ::: "memory");
  else if constexpr (DN == 2) asm volatile("s_waitcnt vmcnt(8) lgkmcnt(0)" ::: "memory");
  else asm volatile("s_waitcnt vmcnt(6) lgkmcnt(0)" ::: "memory");
  __builtin_amdgcn_sched_barrier(0);
  __builtin_amdgcn_s_setprio(1);
#pragma unroll
  for (int m = 0; m < 4; ++m)
#pragma unroll
    for (int n = 0; n < 4; ++n)
      acc[m][n] = __builtin_amdgcn_mfma_f32_16x16x32_bf16(aE[m], b0[n], acc[m][n], 0, 0, 0);
  __builtin_amdgcn_s_setprio(0);
  // PE
#pragma unroll
  for (int m = 0; m < 4; ++m)
    aE[m] = *(const bf16x8*)(Ab + voffA[m] + kAE);
  // W2
  if constexpr (DN == 2) asm volatile("s_waitcnt vmcnt(8) lgkmcnt(0)" ::: "memory");
  else asm volatile("s_waitcnt vmcnt(6) lgkmcnt(0)" ::: "memory");
  __builtin_amdgcn_sched_barrier(0);
  __builtin_amdgcn_s_setprio(1);
#pragma unroll
  for (int m = 0; m < 4; ++m)
#pragma unroll
    for (int n = 0; n < 4; ++n)
      acc[m][n] = __builtin_amdgcn_mfma_f32_16x16x32_bf16(aO[m], TK ? b1[n] : b0[n],
                                                          acc[m][n], 0, 0, 0);
  __builtin_amdgcn_s_setprio(0);
  // PO
#pragma unroll
  for (int m = 0; m < 4; ++m)
    aO[m] = *(const bf16x8*)(Ab + voffA[m] + kAO);
  FENCE;
  __builtin_amdgcn_s_barrier();
  FENCE;
}

__global__ __launch_bounds__(256, 3) void gemm_argmin_k(const __bf16* __restrict__ A,
                                                        const __bf16* __restrict__ B,
                                                        const float* __restrict__ b2,
                                                        unsigned long long* __restrict__ best) {
  __shared__ __align__(16) char lds[49152];
  const int tid = threadIdx.x;
  const int lane = tid & 63;
  const int wid = tid >> 6;   // 0..3
  const int wm = wid >> 1;    // 2 wave-rows (64 rows each)
  const int wn = wid & 1;     // 2 wave-cols (64 cols each)

  // XCD-chunk swizzle (3088 % 8 == 0 -> bijective): 8 M-blocks of a B-panel
  // land on one XCD -> panel fetched into L2 once (R6: FETCH 606->64 MB).
  const int d = blockIdx.x;
  const int o = (d & 7) * 386 + (d >> 3);
  const int bm = (o & 7) * 128;
  const int bn = (o >> 3) * 128;

  const int r = lane & 15, g = lane >> 4;
  const int rh = r >> 1;
  const unsigned lds0 =
      (unsigned)(uintptr_t)(const __attribute__((address_space(3))) char*)(const char*)lds;
  const unsigned bRead = lds0 + wn * 4096 + rh * 128 + (r & 1) * 64 + (((g + rh) & 3) << 4);

  // A per-lane byte offsets, fragment-ordered layout:
  const char* Ab = (const char*)A;
  int voffA[4];
#pragma unroll
  for (int m = 0; m < 4; ++m)
    voffA[m] = ((bm >> 4) + wm * 4 + m) * 1024 + lane * 16;

  // B stage-side lane mapping (inverse of the slot swizzle)
  const int srow = 2 * (tid >> 3) + ((tid >> 2) & 1);
  const int sc16 = ((tid & 3) - (tid >> 3)) & 3;
  const char* srcBt = (const char*)B + (size_t)(bn + srow) * 2048 + sc16 * 16;
  char* stB = (char*)lds + tid * 16;

  f32x4 acc[4][4] = {};
  bf16x8 aE[4], aO[4];

  // prologue: stage B phys tiles 0,1 -> regions 0,1; A(0)->aE, A(16)->aO.
  // vmcnt(10) retains {tile-1 stage(2), aE(4), aO(4)} -> forces tile-0 stage
  // (published by this barrier, read at phase 0).
  gll16(srcBt + 0, stB + 0);
  gll16(srcBt + 0 + 131072, stB + 4096);
  gll16(srcBt + 64, stB + 8192);
  gll16(srcBt + 64 + 131072, stB + 8192 + 4096);
#pragma unroll
  for (int m = 0; m < 4; ++m)
    aE[m] = *(const bf16x8*)(Ab + voffA[m]);
#pragma unroll
  for (int m = 0; m < 4; ++m)
    aO[m] = *(const bf16x8*)(Ab + voffA[m] + 16 * 65536);
  asm volatile("s_waitcnt vmcnt(10)" ::: "memory");
  FENCE;
  __builtin_amdgcn_s_barrier();
  FENCE;

  // 24 straight-line superphases (K fully unrolled)
  phase_op<0>(acc, aE, aO, Ab, voffA, srcBt, stB, bRead);
  phase_op<1>(acc, aE, aO, Ab, voffA, srcBt, stB, bRead);
  phase_op<2>(acc, aE, aO, Ab, voffA, srcBt, stB, bRead);
  phase_op<3>(acc, aE, aO, Ab, voffA, srcBt, stB, bRead);
  phase_op<4>(acc, aE, aO, Ab, voffA, srcBt, stB, bRead);
  phase_op<5>(acc, aE, aO, Ab, voffA, srcBt, stB, bRead);
  phase_op<6>(acc, aE, aO, Ab, voffA, srcBt, stB, bRead);
  phase_op<7>(acc, aE, aO, Ab, voffA, srcBt, stB, bRead);
  phase_op<8>(acc, aE, aO, Ab, voffA, srcBt, stB, bRead);
  phase_op<9>(acc, aE, aO, Ab, voffA, srcBt, stB, bRead);
  phase_op<10>(acc, aE, aO, Ab, voffA, srcBt, stB, bRead);
  phase_op<11>(acc, aE, aO, Ab, voffA, srcBt, stB, bRead);
  phase_op<12>(acc, aE, aO, Ab, voffA, srcBt, stB, bRead);
  phase_op<13>(acc, aE, aO, Ab, voffA, srcBt, stB, bRead);
  phase_op<14>(acc, aE, aO, Ab, voffA, srcBt, stB, bRead);
  phase_op<15>(acc, aE, aO, Ab, voffA, srcBt, stB, bRead);
  phase_op<16>(acc, aE, aO, Ab, voffA, srcBt, stB, bRead);
  phase_op<17>(acc, aE, aO, Ab, voffA, srcBt, stB, bRead);
  phase_op<18>(acc, aE, aO, Ab, voffA, srcBt, stB, bRead);
  phase_op<19>(acc, aE, aO, Ab, voffA, srcBt, stB, bRead);
  phase_op<20>(acc, aE, aO, Ab, voffA, srcBt, stB, bRead);
  phase_op<21>(acc, aE, aO, Ab, voffA, srcBt, stB, bRead);
  phase_op<22>(acc, aE, aO, Ab, voffA, srcBt, stB, bRead);
  phase_op<23>(acc, aE, aO, Ab, voffA, srcBt, stB, bRead);

  // epilogue: fused argmin. C/D map: col = lane&15, row = (lane>>4)*4 + reg.
  float bb[4];
#pragma unroll
  for (int n = 0; n < 4; ++n) bb[n] = b2[bn + wn * 64 + n * 16 + r];
#pragma unroll
  for (int m = 0; m < 4; ++m) {
#pragma unroll
    for (int reg = 0; reg < 4; ++reg) {
      unsigned long long pk = ~0ull;
#pragma unroll
      for (int n = 0; n < 4; ++n) {
        float s = bb[n] - 2.0f * acc[m][n][reg];
        unsigned long long cand = pack_sv(s, (unsigned)(bn + wn * 64 + n * 16 + r));
        pk = (cand < pk) ? cand : pk;
      }
#pragma unroll
      for (int msk = 1; msk < 16; msk <<= 1) {
        unsigned long long o2 = __shfl_xor(pk, msk);
        pk = (o2 < pk) ? o2 : pk;
      }
      if (r == 0) atomicMin(&best[bm + wm * 64 + m * 16 + g * 4 + reg], pk);
    }
  }
}

// Fallback (small ws): exact fp32 squared distance, fused argmin.
__global__ __launch_bounds__(256) void naive_argmin_k(const float* __restrict__ A,
                                                      const float* __restrict__ B,
                                                      unsigned long long* __restrict__ best) {
  __shared__ float arow[ND];
  int p = blockIdx.y;
  unsigned v = blockIdx.x * 256 + threadIdx.x;
  for (int i = threadIdx.x; i < ND; i += 256) arow[i] = A[(size_t)p * ND + i];
  __syncthreads();
  const float4* br = (const float4*)(B + (size_t)v * ND);
  float s = 0.f;
#pragma unroll 4
  for (int i = 0; i < ND / 4; ++i) {
    float4 b = br[i];
    const float4 a = *(const float4*)&arow[i * 4];
    float d0 = a.x - b.x, d1 = a.y - b.y, d2 = a.z - b.z, d3 = a.w - b.w;
    s += d0 * d0 + d1 * d1 + d2 * d2 + d3 * d3;
  }
  unsigned long long pk = pack_sv(s, v);
#pragma unroll
  for (int msk = 1; msk < 64; msk <<= 1) {
    unsigned long long o = __shfl_xor(pk, msk);
    pk = (o < pk) ? o : pk;
  }
  if ((threadIdx.x & 63) == 0) atomicMin(&best[p], pk);
}

// Gather winning rows + ids (ids written as float, d_out is read as flat f32).
__global__ __launch_bounds__(128) void gather_k(const unsigned long long* __restrict__ best,
                                                const float* __restrict__ clip,
                                                float* __restrict__ out) {
  int p = blockIdx.x;
  unsigned long long pk = best[p];
  unsigned v = (unsigned)(pk & 0xffffffffull);
  const float4* src = (const float4*)(clip + (size_t)v * ND);
  float4* dst = (float4*)(out + (size_t)p * ND);
  dst[threadIdx.x] = src[threadIdx.x];
  if (threadIdx.x == 0) out[(size_t)NP * ND + p] = (float)v;
}

extern "C" void kernel_launch(void* const* d_in, const int* in_sizes, int n_in,
                              void* d_out, int out_size, void* d_ws, size_t ws_size,
                              hipStream_t stream) {
  const float* prompt = (const float*)d_in[0];
  const float* clip = (const float*)d_in[1];
  float* out = (float*)d_out;

  // workspace layout
  size_t off = 0;
  unsigned long long* best = (unsigned long long*)d_ws;
  off += (size_t)NP * 8;
  float* b2 = (float*)((char*)d_ws + off);
  off += (size_t)NV * 4;
  off = (off + 255) & ~(size_t)255;
  __bf16* Ap = (__bf16*)((char*)d_ws + off);
  off += (size_t)NP * 1024 * 2;                // 2 MiB  fragment-ordered
  __bf16* Bp = (__bf16*)((char*)d_ws + off);
  off += (size_t)NV * 1024 * 2;                // 96.5 MiB [hi|lo] row-major
  const size_t need = off;

  if (ws_size >= need) {
    hipMemsetAsync(best, 0xFF, (size_t)NP * 8, stream);
    pack_a_k<<<NP / 4, 256, 0, stream>>>(prompt, Ap);
    pack_b_k<<<NV / 4, 256, 0, stream>>>(clip, Bp, b2);
    gemm_argmin_k<<<dim3(8 * 386), 256, 0, stream>>>(Ap, Bp, b2, best);
    gather_k<<<NP, 128, 0, stream>>>(best, clip, out);
  } else {
    // fallback: exact fp32, needs only the 8 KiB `best` array
    hipMemsetAsync(best, 0xFF, (size_t)NP * 8, stream);
    dim3 grid(NV / 256, NP);
    naive_argmin_k<<<grid, 256, 0, stream>>>(prompt, clip, best);
    gather_k<<<NP, 128, 0, stream>>>(best, clip, out);
  }
}

// Round 20
// 213.349 us; speedup vs baseline: 1.1509x; 1.0282x over previous
//
#include <hip/hip_runtime.h>
#include <stdint.h>

#define NP 1024
#define NV 49408
#define ND 512
// B packed: [row][hi(512)|lo(512)] bf16 (2048 B/row).
// A packed FRAGMENT-ORDERED: chunk(t, mb, lane) at byte ((t*64+mb)*64+lane)*16
//   t = phys 32-k tile (0..31: 16 hi, 16 lo), mb = row>>4, lane = g*16+r holds
//   A[mb*16+r][t*32 + g*8 .. +7]. A wave's frag load = 1 KB contiguous.
// Logical K=1536, 3-term split, 32-k steps -> 48 tiles:
//   A phys tile = t & 31                  (ah x16, al x16, ah x16)
//   B phys byte = (t & 15) * 64 + (t >= 32 ? 1024 : 0)   (bh, bh, bl)
#define NTILE 48

typedef __attribute__((ext_vector_type(8))) __bf16 bf16x8;
typedef __attribute__((ext_vector_type(4))) float f32x4;
typedef __attribute__((ext_vector_type(4))) int i32x4;

__device__ inline unsigned long long pack_sv(float s, unsigned v) {
  unsigned u = __float_as_uint(s);
  u = (u & 0x80000000u) ? ~u : (u | 0x80000000u);  // orderable map
  return ((unsigned long long)u << 32) | (unsigned long long)v;
}

// A-pack: bf16 hi/lo split, FRAGMENT-ORDERED layout (see header comment).
__global__ __launch_bounds__(256) void pack_a_k(const float* __restrict__ src,
                                                __bf16* __restrict__ dst) {
  int lane = threadIdx.x & 63;
  int row = blockIdx.x * 4 + (threadIdx.x >> 6);
  const float* r = src + (size_t)row * ND + lane * 8;
  float4 x0 = *(const float4*)r;
  float4 x1 = *(const float4*)(r + 4);
  float xs[8] = {x0.x, x0.y, x0.z, x0.w, x1.x, x1.y, x1.z, x1.w};
  bf16x8 hi, lo;
#pragma unroll
  for (int j = 0; j < 8; ++j) {
    float x = xs[j];
    __bf16 h = (__bf16)x;
    hi[j] = h;
    lo[j] = (__bf16)(x - (float)h);   // exact residual, then RTNE to bf16
  }
  const int mb = row >> 4, rr = row & 15;
  const int tHi = lane >> 2, g = lane & 3;
  size_t cHi = (((size_t)tHi * 64) + mb) * 64 + g * 16 + rr;        // chunk idx
  size_t cLo = (((size_t)(tHi + 16) * 64) + mb) * 64 + g * 16 + rr;
  *(bf16x8*)(dst + cHi * 8) = hi;
  *(bf16x8*)(dst + cLo * 8) = lo;
}

// B-pack: [row][hi|lo] + exact f32 sum of squares per row.
__global__ __launch_bounds__(256) void pack_b_k(const float* __restrict__ src,
                                                __bf16* __restrict__ dst,
                                                float* __restrict__ sumsq) {
  int lane = threadIdx.x & 63;
  int row = blockIdx.x * 4 + (threadIdx.x >> 6);
  const float* r = src + (size_t)row * ND + lane * 8;
  float4 x0 = *(const float4*)r;
  float4 x1 = *(const float4*)(r + 4);
  float xs[8] = {x0.x, x0.y, x0.z, x0.w, x1.x, x1.y, x1.z, x1.w};
  bf16x8 hi, lo;
  float ss = 0.f;
#pragma unroll
  for (int j = 0; j < 8; ++j) {
    float x = xs[j];
    ss += x * x;
    __bf16 h = (__bf16)x;
    hi[j] = h;
    lo[j] = (__bf16)(x - (float)h);
  }
  __bf16* drow = dst + (size_t)row * 1024 + lane * 8;
  *(bf16x8*)drow = hi;
  *(bf16x8*)(drow + 512) = lo;
#pragma unroll
  for (int m = 1; m < 64; m <<= 1) ss += __shfl_xor(ss, m);
  if (lane == 0) sumsq[row] = ss;
}

// ---- 128x128 tile, 4 waves, 3 blocks/CU, SUPER-PHASE (2 K-tiles/barrier) ---
// Best verified configuration (R17: 213 us total, GEMM 179 us = 868 TF,
// within a few percent of the documented plain-HIP 2-barrier-structure
// ceiling; absmax = 0). Each barrier-phase p handles tiles u=2p, v=2p+1
// (32 MFMA/phase).
// B: LDS 6 regions x 8 KB (region = tile % 6), stage distance 4 tiles.
// A: 2 reg buffers; prefetch A(2p+2)->aE AFTER MFMA1(aE) and A(2p+3)->aO
// AFTER MFMA2(aO) (in-order issue: MFMA consumed operands before the
// overwriting load issues -> 2 buffers suffice).
// Per-phase issue order: D x4 (stage 2p+4,2p+5) | b0,b1 ds_reads |
//   W1 = vmcnt(8) lgkmcnt(4) | MFMA1 x16 (aE, b0) | PE x4 (A(2p+2)->aE) |
//   W2 = vmcnt(8) lgkmcnt(0) | MFMA2 x16 (aO, b1) | PO x4 (A(2p+3)->aO) |
//   s_barrier.
// Wait math (newest-first at W1: p.D4, p-1.PO4 -> vmcnt(8) forces p-1.PE
// (=A(2p), consumed by MFMA1) and p-1.D (stages of 2p+2,2p+3: published by
// this barrier, read at p+1)). At W2 (newest: p.PE4, p.D4): forces p-1.PO
// (=A(2p+1)). Stage RAW: tile staged at p, forced at p+1.W1, published at
// p+1 barrier, read at p+2. Region WAR: region (2p+4)%6 last read at p-1
// (b-reads complete by p-1's lgkm waits, before p-1's barrier); overwrite
// issues after that barrier. Wrap tiles 48-51: dead re-stage/load, in-bounds.
// REGISTER BUDGET: acc(64 AGPR) + A(32) + b0/b1(32) + addr ~145 <= 170 from
// (256,3); 3 blocks/CU; LDS 48 KB x3 = 144 <= 160.
// B slot swizzle (R6-verified, 0 conflicts): 16B-slot
//   q(row,c16) = (row>>1)*8 + (row&1)*4 + ((c16 + (row>>1)) & 3)

__device__ __attribute__((always_inline)) static inline
void gll16(const char* src, char* dst) {
  __builtin_amdgcn_global_load_lds(
      (const __attribute__((address_space(1))) void*)src,
      (__attribute__((address_space(3))) void*)dst, 16, 0, 0);
}

__device__ __attribute__((always_inline)) static inline
bf16x8 lds_read(unsigned addr) {
  i32x4 d;
  asm volatile("ds_read_b128 %0, %1" : "=v"(d) : "v"(addr));
  return __builtin_bit_cast(bf16x8, d);
}

#define FENCE asm volatile("" ::: "memory")

__device__ __attribute__((always_inline)) static inline
int bByte(int t) {                    // B phys byte for logical tile t (wraps)
  int tt = (t < NTILE) ? t : t - NTILE;
  return (tt & 15) * 64 + (tt >= 32 ? 1024 : 0);
}

template <int J>   // J = p % 3; read regions 2J, 2J+1; stage (2J+4)%6,(2J+5)%6
__device__ __attribute__((always_inline)) static inline
void phase_op(f32x4 (&acc)[4][4], bf16x8 (&aE)[4], bf16x8 (&aO)[4],
              const char* Ab, const int (&voffA)[4],
              const char* srcBt, char* stB, unsigned bRead, int p) {
  constexpr int R0 = 2 * J, R1 = 2 * J + 1;
  constexpr int S0 = (2 * J + 4) % 6, S1 = (2 * J + 5) % 6;
  const int kB0 = bByte(2 * p + 4), kB1 = bByte(2 * p + 5);
  const int kAE = ((2 * p + 2) & 31) * 65536;
  const int kAO = ((2 * p + 3) & 31) * 65536;
  // D: stage tiles 2p+4, 2p+5
  gll16(srcBt + kB0, stB + S0 * 8192);
  gll16(srcBt + kB0 + 131072, stB + S0 * 8192 + 4096);
  gll16(srcBt + kB1, stB + S1 * 8192);
  gll16(srcBt + kB1 + 131072, stB + S1 * 8192 + 4096);
  // b reads for both sub-tiles (b0 older than b1 in lgkm order)
  bf16x8 b0[4], b1[4];
#pragma unroll
  for (int n = 0; n < 4; ++n) b0[n] = lds_read(bRead + R0 * 8192 + n * 1024);
#pragma unroll
  for (int n = 0; n < 4; ++n) b1[n] = lds_read(bRead + R1 * 8192 + n * 1024);
  asm volatile("s_waitcnt vmcnt(8) lgkmcnt(4)" ::: "memory");
  __builtin_amdgcn_sched_barrier(0);
  __builtin_amdgcn_s_setprio(1);
#pragma unroll
  for (int m = 0; m < 4; ++m)
#pragma unroll
    for (int n = 0; n < 4; ++n)
      acc[m][n] = __builtin_amdgcn_mfma_f32_16x16x32_bf16(aE[m], b0[n], acc[m][n], 0, 0, 0);
  __builtin_amdgcn_s_setprio(0);
  // PE: prefetch A(2p+2) -> aE (safe: MFMA1 consumed aE at issue)
#pragma unroll
  for (int m = 0; m < 4; ++m)
    aE[m] = *(const bf16x8*)(Ab + voffA[m] + kAE);
  asm volatile("s_waitcnt vmcnt(8) lgkmcnt(0)" ::: "memory");
  __builtin_amdgcn_sched_barrier(0);
  __builtin_amdgcn_s_setprio(1);
#pragma unroll
  for (int m = 0; m < 4; ++m)
#pragma unroll
    for (int n = 0; n < 4; ++n)
      acc[m][n] = __builtin_amdgcn_mfma_f32_16x16x32_bf16(aO[m], b1[n], acc[m][n], 0, 0, 0);
  __builtin_amdgcn_s_setprio(0);
  // PO: prefetch A(2p+3) -> aO
#pragma unroll
  for (int m = 0; m < 4; ++m)
    aO[m] = *(const bf16x8*)(Ab + voffA[m] + kAO);
  FENCE;
  __builtin_amdgcn_s_barrier();
  FENCE;
}

__global__ __launch_bounds__(256, 3) void gemm_argmin_k(const __bf16* __restrict__ A,
                                                        const __bf16* __restrict__ B,
                                                        const float* __restrict__ b2,
                                                        unsigned long long* __restrict__ best) {
  __shared__ __align__(16) char lds[49152];
  const int tid = threadIdx.x;
  const int lane = tid & 63;
  const int wid = tid >> 6;   // 0..3
  const int wm = wid >> 1;    // 2 wave-rows (64 rows each)
  const int wn = wid & 1;     // 2 wave-cols (64 cols each)

  // XCD-chunk swizzle (3088 % 8 == 0 -> bijective): 8 M-blocks of a B-panel
  // land on one XCD -> panel fetched into L2 once (R6: FETCH 606->64 MB).
  const int d = blockIdx.x;
  const int o = (d & 7) * 386 + (d >> 3);
  const int bm = (o & 7) * 128;
  const int bn = (o >> 3) * 128;

  const int r = lane & 15, g = lane >> 4;
  const int rh = r >> 1;
  const unsigned lds0 =
      (unsigned)(uintptr_t)(const __attribute__((address_space(3))) char*)(const char*)lds;
  const unsigned bRead = lds0 + wn * 4096 + rh * 128 + (r & 1) * 64 + (((g + rh) & 3) << 4);

  // A per-lane byte offsets, fragment-ordered layout:
  const char* Ab = (const char*)A;
  int voffA[4];
#pragma unroll
  for (int m = 0; m < 4; ++m)
    voffA[m] = ((bm >> 4) + wm * 4 + m) * 1024 + lane * 16;

  // B stage-side lane mapping (inverse of the slot swizzle); 256 threads
  // cover 512 slots of the 8 KB region (rows 0-63 and +64 via 2nd gll16)
  const int srow = 2 * (tid >> 3) + ((tid >> 2) & 1);
  const int sc16 = ((tid & 3) - (tid >> 3)) & 3;
  const char* srcBt = (const char*)B + (size_t)(bn + srow) * 2048 + sc16 * 16;
  char* stB = (char*)lds + tid * 16;

  f32x4 acc[4][4] = {};
  bf16x8 aE[4], aO[4];

  // prologue: stage tiles 0..3 -> regions 0..3; A(0)->aE, A(1)->aO.
  // vmcnt(12) forces tiles 0,1 (read at phase 0); tiles 2,3 forced at
  // phase-0 W1/W2 (published by phase-0 barrier, read at phase 1).
  gll16(srcBt + bByte(0), stB + 0);
  gll16(srcBt + bByte(0) + 131072, stB + 4096);
  gll16(srcBt + bByte(1), stB + 8192);
  gll16(srcBt + bByte(1) + 131072, stB + 8192 + 4096);
  gll16(srcBt + bByte(2), stB + 16384);
  gll16(srcBt + bByte(2) + 131072, stB + 16384 + 4096);
  gll16(srcBt + bByte(3), stB + 24576);
  gll16(srcBt + bByte(3) + 131072, stB + 24576 + 4096);
#pragma unroll
  for (int m = 0; m < 4; ++m)
    aE[m] = *(const bf16x8*)(Ab + voffA[m]);
#pragma unroll
  for (int m = 0; m < 4; ++m)
    aO[m] = *(const bf16x8*)(Ab + voffA[m] + 65536);
  asm volatile("s_waitcnt vmcnt(12)" ::: "memory");
  FENCE;
  __builtin_amdgcn_s_barrier();
  FENCE;

#pragma unroll 1
  for (int it = 0; it < 8; ++it) {
    const int p0 = 3 * it;
    phase_op<0>(acc, aE, aO, Ab, voffA, srcBt, stB, bRead, p0 + 0);
    phase_op<1>(acc, aE, aO, Ab, voffA, srcBt, stB, bRead, p0 + 1);
    phase_op<2>(acc, aE, aO, Ab, voffA, srcBt, stB, bRead, p0 + 2);
  }

  // epilogue: fused argmin. C/D map: col = lane&15, row = (lane>>4)*4 + reg.
  float bb[4];
#pragma unroll
  for (int n = 0; n < 4; ++n) bb[n] = b2[bn + wn * 64 + n * 16 + r];
#pragma unroll
  for (int m = 0; m < 4; ++m) {
#pragma unroll
    for (int reg = 0; reg < 4; ++reg) {
      unsigned long long pk = ~0ull;
#pragma unroll
      for (int n = 0; n < 4; ++n) {
        float s = bb[n] - 2.0f * acc[m][n][reg];
        unsigned long long cand = pack_sv(s, (unsigned)(bn + wn * 64 + n * 16 + r));
        pk = (cand < pk) ? cand : pk;
      }
#pragma unroll
      for (int msk = 1; msk < 16; msk <<= 1) {
        unsigned long long o2 = __shfl_xor(pk, msk);
        pk = (o2 < pk) ? o2 : pk;
      }
      if (r == 0) atomicMin(&best[bm + wm * 64 + m * 16 + g * 4 + reg], pk);
    }
  }
}

// Fallback (small ws): exact fp32 squared distance, fused argmin.
__global__ __launch_bounds__(256) void naive_argmin_k(const float* __restrict__ A,
                                                      const float* __restrict__ B,
                                                      unsigned long long* __restrict__ best) {
  __shared__ float arow[ND];
  int p = blockIdx.y;
  unsigned v = blockIdx.x * 256 + threadIdx.x;
  for (int i = threadIdx.x; i < ND; i += 256) arow[i] = A[(size_t)p * ND + i];
  __syncthreads();
  const float4* br = (const float4*)(B + (size_t)v * ND);
  float s = 0.f;
#pragma unroll 4
  for (int i = 0; i < ND / 4; ++i) {
    float4 b = br[i];
    const float4 a = *(const float4*)&arow[i * 4];
    float d0 = a.x - b.x, d1 = a.y - b.y, d2 = a.z - b.z, d3 = a.w - b.w;
    s += d0 * d0 + d1 * d1 + d2 * d2 + d3 * d3;
  }
  unsigned long long pk = pack_sv(s, v);
#pragma unroll
  for (int msk = 1; msk < 64; msk <<= 1) {
    unsigned long long o = __shfl_xor(pk, msk);
    pk = (o < pk) ? o : pk;
  }
  if ((threadIdx.x & 63) == 0) atomicMin(&best[p], pk);
}

// Gather winning rows + ids (ids written as float, d_out is read as flat f32).
__global__ __launch_bounds__(128) void gather_k(const unsigned long long* __restrict__ best,
                                                const float* __restrict__ clip,
                                                float* __restrict__ out) {
  int p = blockIdx.x;
  unsigned long long pk = best[p];
  unsigned v = (unsigned)(pk & 0xffffffffull);
  const float4* src = (const float4*)(clip + (size_t)v * ND);
  float4* dst = (float4*)(out + (size_t)p * ND);
  dst[threadIdx.x] = src[threadIdx.x];
  if (threadIdx.x == 0) out[(size_t)NP * ND + p] = (float)v;
}

extern "C" void kernel_launch(void* const* d_in, const int* in_sizes, int n_in,
                              void* d_out, int out_size, void* d_ws, size_t ws_size,
                              hipStream_t stream) {
  const float* prompt = (const float*)d_in[0];
  const float* clip = (const float*)d_in[1];
  float* out = (float*)d_out;

  // workspace layout
  size_t off = 0;
  unsigned long long* best = (unsigned long long*)d_ws;
  off += (size_t)NP * 8;
  float* b2 = (float*)((char*)d_ws + off);
  off += (size_t)NV * 4;
  off = (off + 255) & ~(size_t)255;
  __bf16* Ap = (__bf16*)((char*)d_ws + off);
  off += (size_t)NP * 1024 * 2;                // 2 MiB  fragment-ordered
  __bf16* Bp = (__bf16*)((char*)d_ws + off);
  off += (size_t)NV * 1024 * 2;                // 96.5 MiB [hi|lo]
  const size_t need = off;

  if (ws_size >= need) {
    hipMemsetAsync(best, 0xFF, (size_t)NP * 8, stream);
    pack_a_k<<<NP / 4, 256, 0, stream>>>(prompt, Ap);
    pack_b_k<<<NV / 4, 256, 0, stream>>>(clip, Bp, b2);
    gemm_argmin_k<<<dim3(8 * 386), 256, 0, stream>>>(Ap, Bp, b2, best);
    gather_k<<<NP, 128, 0, stream>>>(best, clip, out);
  } else {
    // fallback: exact fp32, needs only the 8 KiB `best` array
    hipMemsetAsync(best, 0xFF, (size_t)NP * 8, stream);
    dim3 grid(NV / 256, NP);
    naive_argmin_k<<<grid, 256, 0, stream>>>(prompt, clip, best);
    gather_k<<<NP, 128, 0, stream>>>(best, clip, out);
  }
}